// Round 2
// baseline (296.191 us; speedup 1.0000x reference)
//
#include <hip/hip_runtime.h>
#include <hip/hip_bf16.h>

using bf16 = __hip_bfloat16;

#define K 25
#define B 256

// ---------------------------------------------------------------------------
// Dtype detection. flags[0]=1 -> float tensors are bf16-packed, 0 -> fp32.
// flags[1]=1 -> knn indices are int64, 0 -> int32.
// ---------------------------------------------------------------------------
__global__ void detect_kernel(const unsigned int* __restrict__ xw,
                              const unsigned int* __restrict__ knnw,
                              int* __restrict__ flags) {
  if (threadIdx.x == 0) {
    int weird = 0;
    for (int i = 0; i < 64; ++i) {
      unsigned int u = xw[i * 997];
      unsigned int e = (u >> 23) & 0xFF;
      if (e >= 192 || e <= 30) ++weird;
    }
    flags[0] = (weird >= 32) ? 1 : 0;
  } else if (threadIdx.x == 1) {
    int nz = 0;
    for (int i = 0; i < 64; ++i) {
      if (knnw[2 * i + 1] != 0) ++nz;
    }
    flags[1] = (nz == 0) ? 1 : 0;
  }
}

__device__ __forceinline__ float load_f(const void* p, size_t i, int fdt) {
  if (fdt) return __bfloat162float(((const bf16*)p)[i]);
  return ((const float*)p)[i];
}

__device__ __forceinline__ int load_idx(const void* p, size_t i, int idt) {
  if (idt) return (int)(((const long long*)p)[i]);
  return ((const int*)p)[i];
}

// ---------------------------------------------------------------------------
// Transpose x (256 x 28800, row-major) -> xT (28800 x 256 bf16)
// ---------------------------------------------------------------------------
__global__ __launch_bounds__(256) void transpose_kernel(const void* __restrict__ x,
                                                        bf16* __restrict__ xT,
                                                        const int* __restrict__ flags) {
  const int fdt = flags[0];
  __shared__ bf16 tile[32][33];
  const int f0 = blockIdx.x * 32;
  const int b0 = blockIdx.y * 32;
  const int t = threadIdx.x;
  const int tf = t & 31;
  const int tq = t >> 5;
#pragma unroll
  for (int i = 0; i < 4; ++i) {
    const int bl = tq + i * 8;
    const size_t src = (size_t)(b0 + bl) * 28800 + (f0 + tf);
    bf16 v;
    if (fdt) v = ((const bf16*)x)[src];
    else     v = __float2bfloat16(((const float*)x)[src]);
    tile[bl][tf] = v;
  }
  __syncthreads();
#pragma unroll
  for (int i = 0; i < 4; ++i) {
    const int fl = tq + i * 8;
    xT[(size_t)(f0 + fl) * B + (b0 + tf)] = tile[tf][fl];
  }
}

// ---------------------------------------------------------------------------
// One LCN layer, both channels (blockIdx.y = channel).
// ---------------------------------------------------------------------------
__global__ __launch_bounds__(256) void lcn_layer(const bf16* __restrict__ inT,
                                                 const void* __restrict__ knn,
                                                 const void* __restrict__ wp,
                                                 const void* __restrict__ bp,
                                                 const void* __restrict__ wn,
                                                 const void* __restrict__ bn,
                                                 bf16* __restrict__ outT,
                                                 const int* __restrict__ flags,
                                                 int prev, int dout) {
  const int fdt = flags[0];
  const int idt = flags[1];
  const int d = blockIdx.x;
  const int ch = blockIdx.y;
  const int b = threadIdx.x;
  const void* w = ch ? wn : wp;
  const void* bias = ch ? bn : bp;
  const bf16* in = inT + (size_t)ch * prev * B;

  float acc = 0.0f;
#pragma unroll
  for (int k = 0; k < K; ++k) {
    const int r = load_idx(knn, (size_t)d * K + k, idt);
    const float v = __bfloat162float(in[(size_t)r * B + b]);
    const float wk = load_f(w, (size_t)d * K + k, fdt);
    acc = fmaf(wk, v, acc);
  }
  acc += load_f(bias, d, fdt);
  acc = fmaxf(acc, 0.0f);
  outT[((size_t)ch * dout + d) * B + b] = __float2bfloat16(acc);
}

// ---------------------------------------------------------------------------
// Per-channel fc: y[ch][o][b] = sum_d fw[o][d] * h2[ch][d][b]   (fp32 atomics)
// ---------------------------------------------------------------------------
__global__ __launch_bounds__(256) void fc_kernel(const bf16* __restrict__ h2,
                                                 const void* __restrict__ fpw,
                                                 const void* __restrict__ fnw,
                                                 float* __restrict__ y,
                                                 const int* __restrict__ flags) {
  const int fdt = flags[0];
  const int ch = blockIdx.y;
  const int b = threadIdx.x;
  const void* fw = ch ? fnw : fpw;
  const bf16* h = h2 + (size_t)ch * 1800 * B;
  const int d0 = blockIdx.x * 225;

  float a0 = 0.0f, a1 = 0.0f;
  for (int d = d0; d < d0 + 225; ++d) {
    const float v = __bfloat162float(h[(size_t)d * B + b]);
    a0 = fmaf(load_f(fw, d, fdt), v, a0);
    a1 = fmaf(load_f(fw, 1800 + d, fdt), v, a1);
  }
  atomicAdd(&y[(ch * 2 + 0) * B + b], a0);
  atomicAdd(&y[(ch * 2 + 1) * B + b], a1);
}

// ---------------------------------------------------------------------------
// Combine + write output in the detected dtype.
// ---------------------------------------------------------------------------
__global__ __launch_bounds__(256) void final_kernel(const float* __restrict__ y,
                                                    const void* __restrict__ fpb,
                                                    const void* __restrict__ fnb,
                                                    const void* __restrict__ f3w,
                                                    const void* __restrict__ f3b,
                                                    void* __restrict__ out,
                                                    const int* __restrict__ flags) {
  const int fdt = flags[0];
  const int b = threadIdx.x;
  float h0 = fmaxf(y[0 * B + b] + load_f(fpb, 0, fdt), 0.0f);
  float h1 = fmaxf(y[1 * B + b] + load_f(fpb, 1, fdt), 0.0f);
  float h2 = fmaxf(y[2 * B + b] + load_f(fnb, 0, fdt), 0.0f);
  float h3 = fmaxf(y[3 * B + b] + load_f(fnb, 1, fdt), 0.0f);
#pragma unroll
  for (int o = 0; o < 2; ++o) {
    float r = load_f(f3b, o, fdt);
    r = fmaf(load_f(f3w, o * 4 + 0, fdt), h0, r);
    r = fmaf(load_f(f3w, o * 4 + 1, fdt), h1, r);
    r = fmaf(load_f(f3w, o * 4 + 2, fdt), h2, r);
    r = fmaf(load_f(f3w, o * 4 + 3, fdt), h3, r);
    if (fdt) ((bf16*)out)[b * 2 + o] = __float2bfloat16(r);
    else     ((float*)out)[b * 2 + o] = r;
  }
}

extern "C" void kernel_launch(void* const* d_in, const int* in_sizes, int n_in,
                              void* d_out, int out_size, void* d_ws, size_t ws_size,
                              hipStream_t stream) {
  const void* x    = d_in[0];
  const void* knn0 = d_in[1];
  const void* knn1 = d_in[2];
  const void* knn2 = d_in[3];
  const void* wp0  = d_in[4];
  const void* bp0  = d_in[5];
  const void* wp1  = d_in[6];
  const void* bp1  = d_in[7];
  const void* wp2  = d_in[8];
  const void* bp2  = d_in[9];
  const void* fcpw = d_in[10];
  const void* fcpb = d_in[11];
  const void* wn0  = d_in[12];
  const void* bn0  = d_in[13];
  const void* wn1  = d_in[14];
  const void* bn1  = d_in[15];
  const void* wn2  = d_in[16];
  const void* bn2  = d_in[17];
  const void* fcnw = d_in[18];
  const void* fcnb = d_in[19];
  const void* f3w  = d_in[20];
  const void* f3b  = d_in[21];

  char* ws = (char*)d_ws;
  bf16* xT = (bf16*)(ws);                    // 14,745,600 B
  bf16* h0 = (bf16*)(ws + 14745600);         //  7,372,800 B
  bf16* h1 = (bf16*)(ws + 22118400);         //  3,686,400 B
  bf16* h2 = (bf16*)(ws + 25804800);         //  1,843,200 B
  float* y = (float*)(ws + 27648000);        //      4,096 B
  int* flags = (int*)(ws + 27652096);        //         64 B

  hipMemsetAsync(y, 0, 1024 * sizeof(float), stream);

  detect_kernel<<<1, 64, 0, stream>>>((const unsigned int*)x,
                                      (const unsigned int*)knn0, flags);

  transpose_kernel<<<dim3(900, 8), 256, 0, stream>>>(x, xT, flags);

  lcn_layer<<<dim3(7200, 2), 256, 0, stream>>>(xT, knn0, wp0, bp0, wn0, bn0, h0,
                                               flags, 14400, 7200);
  lcn_layer<<<dim3(3600, 2), 256, 0, stream>>>(h0, knn1, wp1, bp1, wn1, bn1, h1,
                                               flags, 7200, 3600);
  lcn_layer<<<dim3(1800, 2), 256, 0, stream>>>(h1, knn2, wp2, bp2, wn2, bn2, h2,
                                               flags, 3600, 1800);

  fc_kernel<<<dim3(8, 2), 256, 0, stream>>>(h2, fcpw, fcnw, y, flags);

  final_kernel<<<1, 256, 0, stream>>>(y, fcpb, fcnb, f3w, f3b, d_out, flags);
}

// Round 3
// 177.668 us; speedup vs baseline: 1.6671x; 1.6671x over previous
//
#include <hip/hip_runtime.h>
#include <hip/hip_bf16.h>

using bf16 = __hip_bfloat16;

#define K 25
#define B 256

// ---------------------------------------------------------------------------
// bf16 bit helpers (avoid relying on __hip_bfloat16 member names)
// ---------------------------------------------------------------------------
__device__ __forceinline__ float b2f(ushort u) {
  unsigned int w = ((unsigned int)u) << 16;
  float f;
  __builtin_memcpy(&f, &w, 4);
  return f;
}
__device__ __forceinline__ ushort f2b(float f) {
  bf16 h = __float2bfloat16(f);
  ushort u;
  __builtin_memcpy(&u, &h, 2);
  return u;
}

// ---------------------------------------------------------------------------
// Dtype detection. flags[0]=1 -> float tensors are bf16-packed, 0 -> fp32.
// flags[1]=1 -> knn indices are int64, 0 -> int32.
// ---------------------------------------------------------------------------
__global__ void detect_kernel(const unsigned int* __restrict__ xw,
                              const unsigned int* __restrict__ knnw,
                              int* __restrict__ flags) {
  if (threadIdx.x == 0) {
    int weird = 0;
    for (int i = 0; i < 64; ++i) {
      unsigned int u = xw[i * 997];
      unsigned int e = (u >> 23) & 0xFF;
      if (e >= 192 || e <= 30) ++weird;
    }
    flags[0] = (weird >= 32) ? 1 : 0;
  } else if (threadIdx.x == 1) {
    int nz = 0;
    for (int i = 0; i < 64; ++i) {
      if (knnw[2 * i + 1] != 0) ++nz;
    }
    flags[1] = (nz == 0) ? 1 : 0;
  }
}

__device__ __forceinline__ float load_f(const void* p, size_t i, int fdt) {
  if (fdt) return __bfloat162float(((const bf16*)p)[i]);
  return ((const float*)p)[i];
}

// ---------------------------------------------------------------------------
// Transpose x (256 x 28800, row-major) -> xT (28800 x 256 bf16)
// 64x64 tiles, fp32 LDS tile padded to 65 words (conflict-free both phases).
// grid (450, 4)
// ---------------------------------------------------------------------------
__global__ __launch_bounds__(256) void transpose_kernel(const void* __restrict__ x,
                                                        bf16* __restrict__ xT,
                                                        const int* __restrict__ flags) {
  const int fdt = flags[0];
  __shared__ float tile[64][65];
  const int f0 = blockIdx.x * 64;
  const int b0 = blockIdx.y * 64;
  const int t = threadIdx.x;
  if (fdt) {
    const bf16* xp = (const bf16*)x;
#pragma unroll
    for (int i = 0; i < 16; ++i) {
      const int lin = t + i * 256;
      const int bl = lin >> 6, fl = lin & 63;
      tile[bl][fl] = __bfloat162float(xp[(size_t)(b0 + bl) * 28800 + (f0 + fl)]);
    }
  } else {
    const float* xp = (const float*)x;
#pragma unroll
    for (int i = 0; i < 16; ++i) {
      const int lin = t + i * 256;
      const int bl = lin >> 6, fl = lin & 63;
      tile[bl][fl] = xp[(size_t)(b0 + bl) * 28800 + (f0 + fl)];
    }
  }
  __syncthreads();
#pragma unroll
  for (int i = 0; i < 16; ++i) {
    const int lin = t + i * 256;
    const int fl = lin >> 6, bl = lin & 63;
    ((ushort*)xT)[(size_t)(f0 + fl) * B + (b0 + bl)] = f2b(tile[bl][fl]);
  }
}

// ---------------------------------------------------------------------------
// One LCN layer, both channels. One wave per output dim d; lane covers 4
// batch elems via ushort4 (8 B) loads -> one wave reads exactly one 512 B row.
// 4 dims per block. grid (dout/4, 2).
// ---------------------------------------------------------------------------
__global__ __launch_bounds__(256) void lcn_layer(const bf16* __restrict__ inT,
                                                 const void* __restrict__ knn,
                                                 const void* __restrict__ wp,
                                                 const void* __restrict__ bp,
                                                 const void* __restrict__ wn,
                                                 const void* __restrict__ bn,
                                                 bf16* __restrict__ outT,
                                                 const int* __restrict__ flags,
                                                 int prev, int dout) {
  const int fdt = flags[0];
  const int idt = flags[1];
  const int wave = threadIdx.x >> 6;
  const int lane = threadIdx.x & 63;
  const int d = blockIdx.x * 4 + wave;
  const int ch = blockIdx.y;
  const ushort* in = (const ushort*)(inT + (size_t)ch * prev * B);
  const void* wsel = ch ? wn : wp;
  const void* bsel = ch ? bn : bp;

  // Hoist indices + weights into registers behind single uniform branches.
  int r[K];
  float wk[K];
  if (idt) {
    const long long* ip = (const long long*)knn + (size_t)d * K;
#pragma unroll
    for (int k = 0; k < K; ++k) r[k] = (int)ip[k];
  } else {
    const int* ip = (const int*)knn + (size_t)d * K;
#pragma unroll
    for (int k = 0; k < K; ++k) r[k] = ip[k];
  }
  if (fdt) {
    const ushort* wpp = (const ushort*)wsel + (size_t)d * K;
#pragma unroll
    for (int k = 0; k < K; ++k) wk[k] = b2f(wpp[k]);
  } else {
    const float* wpp = (const float*)wsel + (size_t)d * K;
#pragma unroll
    for (int k = 0; k < K; ++k) wk[k] = wpp[k];
  }
  const float bias = load_f(bsel, d, fdt);

  float a0 = 0.f, a1 = 0.f, a2 = 0.f, a3 = 0.f;
#pragma unroll
  for (int k = 0; k < K; ++k) {
    const ushort4 v = *(const ushort4*)(in + (size_t)r[k] * B + lane * 4);
    a0 = fmaf(wk[k], b2f(v.x), a0);
    a1 = fmaf(wk[k], b2f(v.y), a1);
    a2 = fmaf(wk[k], b2f(v.z), a2);
    a3 = fmaf(wk[k], b2f(v.w), a3);
  }
  a0 = fmaxf(a0 + bias, 0.f);
  a1 = fmaxf(a1 + bias, 0.f);
  a2 = fmaxf(a2 + bias, 0.f);
  a3 = fmaxf(a3 + bias, 0.f);

  ushort4 o;
  o.x = f2b(a0); o.y = f2b(a1); o.z = f2b(a2); o.w = f2b(a3);
  *(ushort4*)((ushort*)outT + ((size_t)ch * dout + d) * B + lane * 4) = o;
}

// ---------------------------------------------------------------------------
// Per-channel fc: y[ch][o][b] += sum over an 8-dim chunk. grid (225, 2).
// ---------------------------------------------------------------------------
__global__ __launch_bounds__(256) void fc_kernel(const bf16* __restrict__ h2,
                                                 const void* __restrict__ fpw,
                                                 const void* __restrict__ fnw,
                                                 float* __restrict__ y,
                                                 const int* __restrict__ flags) {
  const int fdt = flags[0];
  const int ch = blockIdx.y;
  const int b = threadIdx.x;
  const void* fw = ch ? fnw : fpw;
  const ushort* h = (const ushort*)(h2 + (size_t)ch * 1800 * B);
  const int d0 = blockIdx.x * 8;

  float w0[8], w1[8];
  if (fdt) {
    const ushort* fp = (const ushort*)fw;
#pragma unroll
    for (int j = 0; j < 8; ++j) {
      w0[j] = b2f(fp[d0 + j]);
      w1[j] = b2f(fp[1800 + d0 + j]);
    }
  } else {
    const float* fp = (const float*)fw;
#pragma unroll
    for (int j = 0; j < 8; ++j) {
      w0[j] = fp[d0 + j];
      w1[j] = fp[1800 + d0 + j];
    }
  }

  float a0 = 0.f, a1 = 0.f;
#pragma unroll
  for (int j = 0; j < 8; ++j) {
    const float v = b2f(h[(size_t)(d0 + j) * B + b]);
    a0 = fmaf(w0[j], v, a0);
    a1 = fmaf(w1[j], v, a1);
  }
  atomicAdd(&y[(ch * 2 + 0) * B + b], a0);
  atomicAdd(&y[(ch * 2 + 1) * B + b], a1);
}

// ---------------------------------------------------------------------------
// Combine + write output in the detected dtype.
// ---------------------------------------------------------------------------
__global__ __launch_bounds__(256) void final_kernel(const float* __restrict__ y,
                                                    const void* __restrict__ fpb,
                                                    const void* __restrict__ fnb,
                                                    const void* __restrict__ f3w,
                                                    const void* __restrict__ f3b,
                                                    void* __restrict__ out,
                                                    const int* __restrict__ flags) {
  const int fdt = flags[0];
  const int b = threadIdx.x;
  float h0 = fmaxf(y[0 * B + b] + load_f(fpb, 0, fdt), 0.0f);
  float h1 = fmaxf(y[1 * B + b] + load_f(fpb, 1, fdt), 0.0f);
  float h2 = fmaxf(y[2 * B + b] + load_f(fnb, 0, fdt), 0.0f);
  float h3 = fmaxf(y[3 * B + b] + load_f(fnb, 1, fdt), 0.0f);
#pragma unroll
  for (int o = 0; o < 2; ++o) {
    float r = load_f(f3b, o, fdt);
    r = fmaf(load_f(f3w, o * 4 + 0, fdt), h0, r);
    r = fmaf(load_f(f3w, o * 4 + 1, fdt), h1, r);
    r = fmaf(load_f(f3w, o * 4 + 2, fdt), h2, r);
    r = fmaf(load_f(f3w, o * 4 + 3, fdt), h3, r);
    if (fdt) ((bf16*)out)[b * 2 + o] = __float2bfloat16(r);
    else     ((float*)out)[b * 2 + o] = r;
  }
}

extern "C" void kernel_launch(void* const* d_in, const int* in_sizes, int n_in,
                              void* d_out, int out_size, void* d_ws, size_t ws_size,
                              hipStream_t stream) {
  const void* x    = d_in[0];
  const void* knn0 = d_in[1];
  const void* knn1 = d_in[2];
  const void* knn2 = d_in[3];
  const void* wp0  = d_in[4];
  const void* bp0  = d_in[5];
  const void* wp1  = d_in[6];
  const void* bp1  = d_in[7];
  const void* wp2  = d_in[8];
  const void* bp2  = d_in[9];
  const void* fcpw = d_in[10];
  const void* fcpb = d_in[11];
  const void* wn0  = d_in[12];
  const void* bn0  = d_in[13];
  const void* wn1  = d_in[14];
  const void* bn1  = d_in[15];
  const void* wn2  = d_in[16];
  const void* bn2  = d_in[17];
  const void* fcnw = d_in[18];
  const void* fcnb = d_in[19];
  const void* f3w  = d_in[20];
  const void* f3b  = d_in[21];

  char* ws = (char*)d_ws;
  bf16* xT = (bf16*)(ws);                    // 14,745,600 B
  bf16* h0 = (bf16*)(ws + 14745600);         //  7,372,800 B
  bf16* h1 = (bf16*)(ws + 22118400);         //  3,686,400 B
  bf16* h2 = (bf16*)(ws + 25804800);         //  1,843,200 B
  float* y = (float*)(ws + 27648000);        //      4,096 B
  int* flags = (int*)(ws + 27652096);        //         64 B

  hipMemsetAsync(y, 0, 1024 * sizeof(float), stream);

  detect_kernel<<<1, 64, 0, stream>>>((const unsigned int*)x,
                                      (const unsigned int*)knn0, flags);

  transpose_kernel<<<dim3(450, 4), 256, 0, stream>>>(x, xT, flags);

  lcn_layer<<<dim3(1800, 2), 256, 0, stream>>>(xT, knn0, wp0, bp0, wn0, bn0, h0,
                                               flags, 14400, 7200);
  lcn_layer<<<dim3(900, 2), 256, 0, stream>>>(h0, knn1, wp1, bp1, wn1, bn1, h1,
                                              flags, 7200, 3600);
  lcn_layer<<<dim3(450, 2), 256, 0, stream>>>(h1, knn2, wp2, bp2, wn2, bn2, h2,
                                              flags, 3600, 1800);

  fc_kernel<<<dim3(225, 2), 256, 0, stream>>>(h2, fcpw, fcnw, y, flags);

  final_kernel<<<1, 256, 0, stream>>>(y, fcpb, fcnb, f3w, f3b, d_out, flags);
}